// Round 5
// baseline (157.721 us; speedup 1.0000x reference)
//
#include <hip/hip_runtime.h>
#include <hip/hip_bf16.h>
#include <stdint.h>

#define DEV_INLINE __device__ __forceinline__

typedef unsigned short u16;
typedef __attribute__((ext_vector_type(8))) __bf16 bf16x8;
typedef __attribute__((ext_vector_type(4))) float f32x4;

constexpr int Bc = 2, Sc = 2048, Dc = 1024, Hc = 16, HDc = 64;
constexpr int Kdim = 1024;
constexpr size_t SEG4M = 4194304;   // 4M elems
constexpr size_t SEG1M = 1048576;   // 1M elems

DEV_INLINE u16 f32_to_bf16(float f) {
    unsigned int u = __builtin_bit_cast(unsigned int, f);
    unsigned int r = (u + 0x7fffu + ((u >> 16) & 1u)) >> 16;
    return (u16)r;
}

// v_cvt_pk_bf16_f32: low16 = bf16(lo), high16 = bf16(hi)
DEV_INLINE uint32_t cvtpk_bf16(float lo, float hi) {
    uint32_t r;
    asm("v_cvt_pk_bf16_f32 %0, %1, %2" : "=v"(r) : "v"(lo), "v"(hi));
    return r;
}

DEV_INLINE f32x4 mfma16(bf16x8 a, bf16x8 b, f32x4 c) {
    return __builtin_amdgcn_mfma_f32_16x16x32_bf16(a, b, c, 0, 0, 0);
}

// async global->LDS, 16B per lane; lds dest must be wave-uniform base.
DEV_INLINE void gload_lds16(const u16* g, u16* lds) {
    __builtin_amdgcn_global_load_lds(
        (const __attribute__((address_space(1))) void*)g,
        (__attribute__((address_space(3))) void*)lds,
        16, 0, 0);
}

// ---------------- fp32 -> bf16, all 7 tensors in one launch ----------------
__global__ __launch_bounds__(256) void cvt_all_kernel(
        const float* __restrict__ q, const float* __restrict__ k,
        const float* __restrict__ v, const float* __restrict__ wq,
        const float* __restrict__ wk, const float* __restrict__ wv,
        const float* __restrict__ wo, u16* __restrict__ dst) {
    int b = blockIdx.x;
    const float* src; size_t doff; int lb;
    if (b < 2048)      { src = q;  lb = b;        doff = 0; }
    else if (b < 4096) { src = k;  lb = b - 2048; doff = SEG4M; }
    else if (b < 6144) { src = v;  lb = b - 4096; doff = 2 * SEG4M; }
    else if (b < 6656) { src = wq; lb = b - 6144; doff = 3 * SEG4M; }
    else if (b < 7168) { src = wk; lb = b - 6656; doff = 3 * SEG4M + SEG1M; }
    else if (b < 7680) { src = wv; lb = b - 7168; doff = 3 * SEG4M + 2 * SEG1M; }
    else               { src = wo; lb = b - 7680; doff = 3 * SEG4M + 3 * SEG1M; }
    size_t i = ((size_t)lb * 256 + threadIdx.x) * 8;
    float4 a = *reinterpret_cast<const float4*>(src + i);
    float4 c = *reinterpret_cast<const float4*>(src + i + 4);
    union { u16 u[8]; uint4 v4; } o;
    o.u[0] = f32_to_bf16(a.x); o.u[1] = f32_to_bf16(a.y);
    o.u[2] = f32_to_bf16(a.z); o.u[3] = f32_to_bf16(a.w);
    o.u[4] = f32_to_bf16(c.x); o.u[5] = f32_to_bf16(c.y);
    o.u[6] = f32_to_bf16(c.z); o.u[7] = f32_to_bf16(c.w);
    *reinterpret_cast<uint4*>(dst + doff + i) = o.v4;
}

// ---------------- fused QKV projection: 128x128 tiles, global_load_lds -----
// seg 0 -> Qh head-layout (scaled 1/8 * log2(e) for exp2-domain softmax);
// seg 1 -> Kh head-layout; seg 2 -> Vt TRANSPOSED (BH,64,S).
__global__ __launch_bounds__(256, 3) void gemm_qkv_kernel(
        const u16* __restrict__ Xb, const u16* __restrict__ Wb,
        u16* __restrict__ Ob) {
    __shared__ u16 Al[128 * 64];
    __shared__ u16 Bl[128 * 64];
    const int tid = threadIdx.x;
    const int l = tid & 63, w = tid >> 6;
    const int wm = w >> 1, wn = w & 1;
    const int l15 = l & 15, lg = l >> 4;
    const int lr = l >> 3, lc = (l & 7) * 8;

    int bid = blockIdx.x;                       // 768 blocks
    int wid = (bid & 7) * 96 + (bid >> 3);      // XCD-contiguous
    int mt = wid / 24, nt = wid % 24;
    int seg = nt >> 3, ntl = nt & 7;

    const u16* A = Xb + (size_t)seg * SEG4M + (size_t)mt * 128 * Kdim;
    const u16* W = Wb + (size_t)seg * SEG1M + (size_t)ntl * 128 * Kdim;

    f32x4 acc[4][4] = {};

    for (int kt = 0; kt < 16; ++kt) {
        const int kb = kt * 64;
#pragma unroll
        for (int i = 0; i < 4; ++i) {
            int j = w * 4 + i;
            gload_lds16(A + (size_t)(j * 8 + lr) * Kdim + kb + lc, &Al[j * 512]);
            gload_lds16(W + (size_t)(j * 8 + lr) * Kdim + kb + lc, &Bl[j * 512]);
        }
        asm volatile("s_waitcnt vmcnt(0)" ::: "memory");
        __syncthreads();
#pragma unroll
        for (int kk = 0; kk < 2; ++kk) {
            bf16x8 af[4], bfr[4];
#pragma unroll
            for (int mi = 0; mi < 4; ++mi)
                af[mi] = *reinterpret_cast<const bf16x8*>(&Al[(wm * 64 + mi * 16 + l15) * 64 + kk * 32 + lg * 8]);
#pragma unroll
            for (int ni = 0; ni < 4; ++ni)
                bfr[ni] = *reinterpret_cast<const bf16x8*>(&Bl[(wn * 64 + ni * 16 + l15) * 64 + kk * 32 + lg * 8]);
#pragma unroll
            for (int mi = 0; mi < 4; ++mi)
#pragma unroll
                for (int ni = 0; ni < 4; ++ni)
                    acc[mi][ni] = mfma16(af[mi], bfr[ni], acc[mi][ni]);
        }
        __syncthreads();
    }

    const int row0 = mt * 128 + wm * 64;
    const int col0 = ntl * 128 + wn * 64;

    if (seg == 2) {
        // V: write transposed Vt[(bh*64+d)*Sc + s], 4 s-consecutive packed
        u16* outT = Ob + 2 * SEG4M;
#pragma unroll
        for (int mi = 0; mi < 4; ++mi) {
            int m0 = row0 + mi * 16 + lg * 4;    // s base (4 consecutive)
            int b = m0 >> 11, s0 = m0 & 2047;
#pragma unroll
            for (int ni = 0; ni < 4; ++ni) {
                int n = col0 + ni * 16 + l15;
                int h = n >> 6, d = n & 63;
                int bh = b * Hc + h;
                uint2 pk;
                pk.x = ((uint32_t)f32_to_bf16(acc[mi][ni][1]) << 16) | f32_to_bf16(acc[mi][ni][0]);
                pk.y = ((uint32_t)f32_to_bf16(acc[mi][ni][3]) << 16) | f32_to_bf16(acc[mi][ni][2]);
                *reinterpret_cast<uint2*>(outT + ((size_t)bh * 64 + d) * Sc + s0) = pk;
            }
        }
    } else {
        // Q scaled into exp2 domain: 1/sqrt(64) * log2(e)
        const float scale = (seg == 0) ? 0.18033688f : 1.0f;
        u16* out = Ob + (size_t)seg * SEG4M;
#pragma unroll
        for (int mi = 0; mi < 4; ++mi)
#pragma unroll
            for (int r = 0; r < 4; ++r) {
                int m = row0 + mi * 16 + lg * 4 + r;
                int b = m >> 11, s = m & 2047;
#pragma unroll
                for (int ni = 0; ni < 4; ++ni) {
                    int n = col0 + ni * 16 + l15;
                    int h = n >> 6, d = n & 63;
                    out[(((size_t)b * Hc + h) * Sc + s) * HDc + d] =
                        f32_to_bf16(acc[mi][ni][r] * scale);
                }
            }
    }
}

// ---------------- output projection: 128x64 tiles -> fp32 ------------------
__global__ __launch_bounds__(256, 3) void gemm_out_kernel(
        const u16* __restrict__ A0, const u16* __restrict__ W0,
        float* __restrict__ outf) {
    __shared__ u16 Al[128 * 64];
    __shared__ u16 Bl[64 * 64];
    const int tid = threadIdx.x;
    const int l = tid & 63, w = tid >> 6;
    const int l15 = l & 15, lg = l >> 4;
    const int lr = l >> 3, lc = (l & 7) * 8;

    int bid = blockIdx.x;                      // 512 blocks
    int wid = (bid & 7) * 64 + (bid >> 3);
    int mt = wid >> 4, nt = wid & 15;

    const u16* A = A0 + (size_t)mt * 128 * Kdim;
    const u16* W = W0 + (size_t)nt * 64 * Kdim;

    f32x4 acc[2][4] = {};

    for (int kt = 0; kt < 16; ++kt) {
        const int kb = kt * 64;
#pragma unroll
        for (int i = 0; i < 4; ++i) {
            int j = w * 4 + i;
            gload_lds16(A + (size_t)(j * 8 + lr) * Kdim + kb + lc, &Al[j * 512]);
        }
#pragma unroll
        for (int i = 0; i < 2; ++i) {
            int j = w * 2 + i;
            gload_lds16(W + (size_t)(j * 8 + lr) * Kdim + kb + lc, &Bl[j * 512]);
        }
        asm volatile("s_waitcnt vmcnt(0)" ::: "memory");
        __syncthreads();
#pragma unroll
        for (int kk = 0; kk < 2; ++kk) {
            bf16x8 af[2], bfr[4];
#pragma unroll
            for (int mi = 0; mi < 2; ++mi)
                af[mi] = *reinterpret_cast<const bf16x8*>(&Al[(w * 32 + mi * 16 + l15) * 64 + kk * 32 + lg * 8]);
#pragma unroll
            for (int ni = 0; ni < 4; ++ni)
                bfr[ni] = *reinterpret_cast<const bf16x8*>(&Bl[(ni * 16 + l15) * 64 + kk * 32 + lg * 8]);
#pragma unroll
            for (int mi = 0; mi < 2; ++mi)
#pragma unroll
                for (int ni = 0; ni < 4; ++ni)
                    acc[mi][ni] = mfma16(af[mi], bfr[ni], acc[mi][ni]);
        }
        __syncthreads();
    }

#pragma unroll
    for (int mi = 0; mi < 2; ++mi)
#pragma unroll
        for (int r = 0; r < 4; ++r) {
            int m = mt * 128 + w * 32 + mi * 16 + lg * 4 + r;
#pragma unroll
            for (int ni = 0; ni < 4; ++ni) {
                int n = nt * 64 + ni * 16 + l15;
                outf[(size_t)m * 1024 + n] = acc[mi][ni][r];
            }
        }
}

// ---------------- causal flash attention ----------------------------------
// Swapped-operand softmax (lane-local rows), double-buffered K/V (ONE
// barrier per KV tile), work-balanced qt pairing across dispatch rounds,
// exp2-domain softmax (log2e folded into Q scale).
__global__ __launch_bounds__(256, 2) void flash_attn_kernel(
        const u16* __restrict__ Qh, const u16* __restrict__ Kh,
        const u16* __restrict__ Vt, u16* __restrict__ Ctx) {
    __shared__ u16 Ksh[2][64][72];
    __shared__ u16 Vsh[2][64][72];
    __shared__ u16 Psh[4][2][16][72];

    const int tid = threadIdx.x;
    const int l = tid & 63, w = tid >> 6;
    const int l15 = l & 15, lg = l >> 4;

    const int bid = blockIdx.x;
    const int bh = bid & 31;                 // bh%8 pins to one XCD
    // balanced pairing: CU's two blocks get qt summing to 15
    const int qt = (bid < 256) ? (15 - (bid >> 5)) : ((bid >> 5) - 8);
    const int b = bh >> 4, h = bh & 15;
    const int qr0 = qt * 128 + w * 32;       // this wave's 32 q-rows

    // Q fragments (B-operand): lane holds Q[q=qr0+16mi+l15][32kk+8lg .. +7]
    const u16* qb = Qh + ((size_t)bh * Sc + qr0) * 64;
    bf16x8 aq[2][2];
#pragma unroll
    for (int mi = 0; mi < 2; ++mi)
#pragma unroll
        for (int kk = 0; kk < 2; ++kk)
            aq[mi][kk] = *reinterpret_cast<const bf16x8*>(
                qb + (size_t)(mi * 16 + l15) * 64 + kk * 32 + lg * 8);

    // O^T accumulator: o[mi][nd][r] = O[d=nd*16+4lg+r][q=l15+16mi]
    f32x4 o[2][4] = {};
    float m_run[2] = {-1e30f, -1e30f}, l_run[2] = {0.f, 0.f};

    const u16* kb0 = Kh + (size_t)bh * Sc * 64;
    const u16* vb0 = Vt + (size_t)bh * 64 * Sc;
    const int nkt = 2 * qt + 2;              // block trip count
    const int kt_max_w = qr0 >> 6;           // this wave's last active tile

    uint4 rk[2], rv[2];
    auto load_kv = [&](int kt) {
#pragma unroll
        for (int i = 0; i < 2; ++i) {
            int f = i * 256 + tid, r = f >> 3, cc = (f & 7) * 8;
            rk[i] = *reinterpret_cast<const uint4*>(kb0 + ((size_t)kt * 64 + r) * 64 + cc);
            rv[i] = *reinterpret_cast<const uint4*>(vb0 + (size_t)r * Sc + kt * 64 + cc);
        }
    };
    auto store_kv = [&](int buf) {
#pragma unroll
        for (int i = 0; i < 2; ++i) {
            int f = i * 256 + tid, r = f >> 3, cc = (f & 7) * 8;
            *reinterpret_cast<uint4*>(&Ksh[buf][r][cc]) = rk[i];
            *reinterpret_cast<uint4*>(&Vsh[buf][r][cc]) = rv[i];
        }
    };

    // prologue: tile 0 staged, tile 1 in regs
    load_kv(0);
    store_kv(0);
    load_kv(1);
    __syncthreads();

    for (int kt = 0; kt < nkt; ++kt) {
        const int cur = kt & 1;
        if (kt + 1 < nkt) store_kv(cur ^ 1);        // tile kt+1 (regs -> LDS)
        if (kt + 2 < nkt) load_kv(kt + 2);          // issue next global loads

        if (kt <= kt_max_w) {
            // S^T = K Q^T: sc[mi][nk][r] = S[q=l15+16mi][kpos=16nk+4lg+r]
            f32x4 sc[2][4] = {};
#pragma unroll
            for (int kk = 0; kk < 2; ++kk) {
                bf16x8 kf[4];
#pragma unroll
                for (int nk = 0; nk < 4; ++nk)
                    kf[nk] = *reinterpret_cast<const bf16x8*>(&Ksh[cur][nk * 16 + l15][kk * 32 + lg * 8]);
                __builtin_amdgcn_s_setprio(1);
#pragma unroll
                for (int mi = 0; mi < 2; ++mi)
#pragma unroll
                    for (int nk = 0; nk < 4; ++nk)
                        sc[mi][nk] = mfma16(kf[nk], aq[mi][kk], sc[mi][nk]);
                __builtin_amdgcn_s_setprio(0);
            }

            // causal mask only on this wave's diagonal tile
            if (kt == kt_max_w) {
                const int kb = kt * 64 + lg * 4;
#pragma unroll
                for (int mi = 0; mi < 2; ++mi) {
                    const int qg = qr0 + mi * 16 + l15;
#pragma unroll
                    for (int nk = 0; nk < 4; ++nk)
#pragma unroll
                        for (int r = 0; r < 4; ++r)
                            if (kb + nk * 16 + r > qg) sc[mi][nk][r] = -1e30f;
                }
            }

            // lane-local online softmax in exp2 domain (q = l15 lane-fixed)
#pragma unroll
            for (int mi = 0; mi < 2; ++mi) {
                float pmax = -1e30f;
#pragma unroll
                for (int nk = 0; nk < 4; ++nk)
#pragma unroll
                    for (int r = 0; r < 4; ++r) pmax = fmaxf(pmax, sc[mi][nk][r]);
                pmax = fmaxf(pmax, __shfl_xor(pmax, 16));
                pmax = fmaxf(pmax, __shfl_xor(pmax, 32));
                if (pmax > m_run[mi] + 11.5f) {      // defer-max (~8 nats)
                    float alpha = exp2f(m_run[mi] - pmax);
                    l_run[mi] *= alpha;
#pragma unroll
                    for (int nd = 0; nd < 4; ++nd)
#pragma unroll
                        for (int r = 0; r < 4; ++r) o[mi][nd][r] *= alpha;
                    m_run[mi] = pmax;
                }
                float ssum = 0.f;
#pragma unroll
                for (int nk = 0; nk < 4; ++nk)
#pragma unroll
                    for (int r = 0; r < 4; ++r) {
                        float p = exp2f(sc[mi][nk][r] - m_run[mi]);
                        sc[mi][nk][r] = p;
                        ssum += p;
                    }
                ssum += __shfl_xor(ssum, 16);
                ssum += __shfl_xor(ssum, 32);
                l_run[mi] += ssum;
                // pack P row (q=l15) -> Psh[w][mi][q][kpos], 4x ds_write_b64
#pragma unroll
                for (int nk = 0; nk < 4; ++nk) {
                    uint2 pk;
                    pk.x = cvtpk_bf16(sc[mi][nk][0], sc[mi][nk][1]);
                    pk.y = cvtpk_bf16(sc[mi][nk][2], sc[mi][nk][3]);
                    *reinterpret_cast<uint2*>(&Psh[w][mi][l15][nk * 16 + lg * 4]) = pk;
                }
            }
            asm volatile("s_waitcnt lgkmcnt(0)" ::: "memory");
            __builtin_amdgcn_sched_barrier(0);

            // O^T += V^T P^T : mfma(V, P) -> D[d][q]
#pragma unroll
            for (int kk = 0; kk < 2; ++kk) {
                bf16x8 vf[4], pa[2];
#pragma unroll
                for (int nd = 0; nd < 4; ++nd)
                    vf[nd] = *reinterpret_cast<const bf16x8*>(&Vsh[cur][nd * 16 + l15][kk * 32 + lg * 8]);
#pragma unroll
                for (int mi = 0; mi < 2; ++mi)
                    pa[mi] = *reinterpret_cast<const bf16x8*>(&Psh[w][mi][l15][kk * 32 + lg * 8]);
                __builtin_amdgcn_s_setprio(1);
#pragma unroll
                for (int mi = 0; mi < 2; ++mi)
#pragma unroll
                    for (int nd = 0; nd < 4; ++nd)
                        o[mi][nd] = mfma16(vf[nd], pa[mi], o[mi][nd]);
                __builtin_amdgcn_s_setprio(0);
            }
        }
        __syncthreads();   // single barrier per KV tile (double-buffered)
    }

    // epilogue: normalize (per-lane q), write Ctx (B,S,D) bf16, 8B packed
#pragma unroll
    for (int mi = 0; mi < 2; ++mi) {
        float inv = 1.f / l_run[mi];
        int srow = qr0 + mi * 16 + l15;
        size_t base = ((size_t)b * Sc + srow) * Dc + h * 64;
#pragma unroll
        for (int nd = 0; nd < 4; ++nd) {
            uint2 pk;
            pk.x = cvtpk_bf16(o[mi][nd][0] * inv, o[mi][nd][1] * inv);
            pk.y = cvtpk_bf16(o[mi][nd][2] * inv, o[mi][nd][3] * inv);
            *reinterpret_cast<uint2*>(Ctx + base + nd * 16 + lg * 4) = pk;
        }
    }
}

// ---------------------------------------------------------------------------
extern "C" void kernel_launch(void* const* d_in, const int* in_sizes, int n_in,
                              void* d_out, int out_size, void* d_ws, size_t ws_size,
                              hipStream_t stream) {
    const float* q  = (const float*)d_in[0];
    const float* k  = (const float*)d_in[1];
    const float* v  = (const float*)d_in[2];
    const float* Wq = (const float*)d_in[4];
    const float* Wk = (const float*)d_in[5];
    const float* Wv = (const float*)d_in[6];
    const float* Wo = (const float*)d_in[7];

    u16* ws = (u16*)d_ws;
    u16* Xq  = ws;                       // 3 x 4M input bf16 (contiguous)
    u16* Wqb = ws + 3 * SEG4M;           // 4 x 1M weights bf16 (contiguous)
    u16* Wob = Wqb + 3 * SEG1M;
    u16* Qh  = ws + 4 * SEG4M;           // Q head-layout (exp2-scaled)
    u16* Kh  = Qh + SEG4M;               // K head-layout
    u16* Vtr = Kh + SEG4M;               // V TRANSPOSED (written by gemm_qkv)
    u16* Ctx = ws;                       // alias Xq (dead after gemm_qkv)

    // 1) all conversions, one launch
    cvt_all_kernel<<<8192, 256, 0, stream>>>(q, k, v, Wq, Wk, Wv, Wo, ws);

    // 2) fused QKV projection (Q scaled 0.125*log2e; V written pre-transposed)
    gemm_qkv_kernel<<<768, 256, 0, stream>>>(Xq, Wqb, Qh);

    // 3) causal flash attention (dbuf K/V, balanced qt pairing)
    flash_attn_kernel<<<512, 256, 0, stream>>>(Qh, Kh, Vtr, Ctx);

    // 4) output projection -> fp32
    gemm_out_kernel<<<512, 256, 0, stream>>>(Ctx, Wob, (float*)d_out);
}

// Round 6
// 123.945 us; speedup vs baseline: 1.2725x; 1.2725x over previous
//
#include <hip/hip_runtime.h>
#include <hip/hip_bf16.h>
#include <stdint.h>

#define DEV_INLINE __device__ __forceinline__

typedef unsigned short u16;
typedef __attribute__((ext_vector_type(8))) __bf16 bf16x8;
typedef __attribute__((ext_vector_type(4))) float f32x4;

constexpr int Bc = 2, Sc = 2048, Dc = 1024, Hc = 16, HDc = 64;
constexpr int Kdim = 1024;
constexpr size_t SEG4M = 4194304;   // 4M elems
constexpr size_t SEG1M = 1048576;   // 1M elems

DEV_INLINE u16 f32_to_bf16(float f) {
    unsigned int u = __builtin_bit_cast(unsigned int, f);
    unsigned int r = (u + 0x7fffu + ((u >> 16) & 1u)) >> 16;
    return (u16)r;
}

// v_cvt_pk_bf16_f32: low16 = bf16(lo), high16 = bf16(hi)
DEV_INLINE uint32_t cvtpk_bf16(float lo, float hi) {
    uint32_t r;
    asm("v_cvt_pk_bf16_f32 %0, %1, %2" : "=v"(r) : "v"(lo), "v"(hi));
    return r;
}

DEV_INLINE f32x4 mfma16(bf16x8 a, bf16x8 b, f32x4 c) {
    return __builtin_amdgcn_mfma_f32_16x16x32_bf16(a, b, c, 0, 0, 0);
}

// async global->LDS, 16B per lane; lds dest must be wave-uniform base.
DEV_INLINE void gload_lds16(const u16* g, u16* lds) {
    __builtin_amdgcn_global_load_lds(
        (const __attribute__((address_space(1))) void*)g,
        (__attribute__((address_space(3))) void*)lds,
        16, 0, 0);
}

// ---------------- fp32 -> bf16, all 7 tensors in one launch ----------------
__global__ __launch_bounds__(256) void cvt_all_kernel(
        const float* __restrict__ q, const float* __restrict__ k,
        const float* __restrict__ v, const float* __restrict__ wq,
        const float* __restrict__ wk, const float* __restrict__ wv,
        const float* __restrict__ wo, u16* __restrict__ dst) {
    int b = blockIdx.x;
    const float* src; size_t doff; int lb;
    if (b < 2048)      { src = q;  lb = b;        doff = 0; }
    else if (b < 4096) { src = k;  lb = b - 2048; doff = SEG4M; }
    else if (b < 6144) { src = v;  lb = b - 4096; doff = 2 * SEG4M; }
    else if (b < 6656) { src = wq; lb = b - 6144; doff = 3 * SEG4M; }
    else if (b < 7168) { src = wk; lb = b - 6656; doff = 3 * SEG4M + SEG1M; }
    else if (b < 7680) { src = wv; lb = b - 7168; doff = 3 * SEG4M + 2 * SEG1M; }
    else               { src = wo; lb = b - 7680; doff = 3 * SEG4M + 3 * SEG1M; }
    size_t i = ((size_t)lb * 256 + threadIdx.x) * 8;
    float4 a = *reinterpret_cast<const float4*>(src + i);
    float4 c = *reinterpret_cast<const float4*>(src + i + 4);
    union { u16 u[8]; uint4 v4; } o;
    o.u[0] = f32_to_bf16(a.x); o.u[1] = f32_to_bf16(a.y);
    o.u[2] = f32_to_bf16(a.z); o.u[3] = f32_to_bf16(a.w);
    o.u[4] = f32_to_bf16(c.x); o.u[5] = f32_to_bf16(c.y);
    o.u[6] = f32_to_bf16(c.z); o.u[7] = f32_to_bf16(c.w);
    *reinterpret_cast<uint4*>(dst + doff + i) = o.v4;
}

// ---------------- fused QKV projection: 128x128 tiles, global_load_lds -----
// seg 0 -> Qh head-layout (scaled 1/8 * log2(e) for exp2-domain softmax);
// seg 1 -> Kh head-layout; seg 2 -> Vt TRANSPOSED (BH,64,S).
__global__ __launch_bounds__(256, 3) void gemm_qkv_kernel(
        const u16* __restrict__ Xb, const u16* __restrict__ Wb,
        u16* __restrict__ Ob) {
    __shared__ u16 Al[128 * 64];
    __shared__ u16 Bl[128 * 64];
    const int tid = threadIdx.x;
    const int l = tid & 63, w = tid >> 6;
    const int wm = w >> 1, wn = w & 1;
    const int l15 = l & 15, lg = l >> 4;
    const int lr = l >> 3, lc = (l & 7) * 8;

    int bid = blockIdx.x;                       // 768 blocks
    int wid = (bid & 7) * 96 + (bid >> 3);      // XCD-contiguous
    int mt = wid / 24, nt = wid % 24;
    int seg = nt >> 3, ntl = nt & 7;

    const u16* A = Xb + (size_t)seg * SEG4M + (size_t)mt * 128 * Kdim;
    const u16* W = Wb + (size_t)seg * SEG1M + (size_t)ntl * 128 * Kdim;

    f32x4 acc[4][4] = {};

    for (int kt = 0; kt < 16; ++kt) {
        const int kb = kt * 64;
#pragma unroll
        for (int i = 0; i < 4; ++i) {
            int j = w * 4 + i;
            gload_lds16(A + (size_t)(j * 8 + lr) * Kdim + kb + lc, &Al[j * 512]);
            gload_lds16(W + (size_t)(j * 8 + lr) * Kdim + kb + lc, &Bl[j * 512]);
        }
        asm volatile("s_waitcnt vmcnt(0)" ::: "memory");
        __syncthreads();
#pragma unroll
        for (int kk = 0; kk < 2; ++kk) {
            bf16x8 af[4], bfr[4];
#pragma unroll
            for (int mi = 0; mi < 4; ++mi)
                af[mi] = *reinterpret_cast<const bf16x8*>(&Al[(wm * 64 + mi * 16 + l15) * 64 + kk * 32 + lg * 8]);
#pragma unroll
            for (int ni = 0; ni < 4; ++ni)
                bfr[ni] = *reinterpret_cast<const bf16x8*>(&Bl[(wn * 64 + ni * 16 + l15) * 64 + kk * 32 + lg * 8]);
#pragma unroll
            for (int mi = 0; mi < 4; ++mi)
#pragma unroll
                for (int ni = 0; ni < 4; ++ni)
                    acc[mi][ni] = mfma16(af[mi], bfr[ni], acc[mi][ni]);
        }
        __syncthreads();
    }

    const int row0 = mt * 128 + wm * 64;
    const int col0 = ntl * 128 + wn * 64;

    if (seg == 2) {
        // V: write transposed Vt[(bh*64+d)*Sc + s], 4 s-consecutive packed
        u16* outT = Ob + 2 * SEG4M;
#pragma unroll
        for (int mi = 0; mi < 4; ++mi) {
            int m0 = row0 + mi * 16 + lg * 4;    // s base (4 consecutive)
            int b = m0 >> 11, s0 = m0 & 2047;
#pragma unroll
            for (int ni = 0; ni < 4; ++ni) {
                int n = col0 + ni * 16 + l15;
                int h = n >> 6, d = n & 63;
                int bh = b * Hc + h;
                uint2 pk;
                pk.x = ((uint32_t)f32_to_bf16(acc[mi][ni][1]) << 16) | f32_to_bf16(acc[mi][ni][0]);
                pk.y = ((uint32_t)f32_to_bf16(acc[mi][ni][3]) << 16) | f32_to_bf16(acc[mi][ni][2]);
                *reinterpret_cast<uint2*>(outT + ((size_t)bh * 64 + d) * Sc + s0) = pk;
            }
        }
    } else {
        // Q scaled into exp2 domain: 1/sqrt(64) * log2(e)
        const float scale = (seg == 0) ? 0.18033688f : 1.0f;
        u16* out = Ob + (size_t)seg * SEG4M;
#pragma unroll
        for (int mi = 0; mi < 4; ++mi)
#pragma unroll
            for (int r = 0; r < 4; ++r) {
                int m = row0 + mi * 16 + lg * 4 + r;
                int b = m >> 11, s = m & 2047;
#pragma unroll
                for (int ni = 0; ni < 4; ++ni) {
                    int n = col0 + ni * 16 + l15;
                    int h = n >> 6, d = n & 63;
                    out[(((size_t)b * Hc + h) * Sc + s) * HDc + d] =
                        f32_to_bf16(acc[mi][ni][r] * scale);
                }
            }
    }
}

// ---------------- output projection: 128x64 tiles -> fp32 ------------------
__global__ __launch_bounds__(256, 3) void gemm_out_kernel(
        const u16* __restrict__ A0, const u16* __restrict__ W0,
        float* __restrict__ outf) {
    __shared__ u16 Al[128 * 64];
    __shared__ u16 Bl[64 * 64];
    const int tid = threadIdx.x;
    const int l = tid & 63, w = tid >> 6;
    const int l15 = l & 15, lg = l >> 4;
    const int lr = l >> 3, lc = (l & 7) * 8;

    int bid = blockIdx.x;                      // 512 blocks
    int wid = (bid & 7) * 64 + (bid >> 3);
    int mt = wid >> 4, nt = wid & 15;

    const u16* A = A0 + (size_t)mt * 128 * Kdim;
    const u16* W = W0 + (size_t)nt * 64 * Kdim;

    f32x4 acc[2][4] = {};

    for (int kt = 0; kt < 16; ++kt) {
        const int kb = kt * 64;
#pragma unroll
        for (int i = 0; i < 4; ++i) {
            int j = w * 4 + i;
            gload_lds16(A + (size_t)(j * 8 + lr) * Kdim + kb + lc, &Al[j * 512]);
        }
#pragma unroll
        for (int i = 0; i < 2; ++i) {
            int j = w * 2 + i;
            gload_lds16(W + (size_t)(j * 8 + lr) * Kdim + kb + lc, &Bl[j * 512]);
        }
        asm volatile("s_waitcnt vmcnt(0)" ::: "memory");
        __syncthreads();
#pragma unroll
        for (int kk = 0; kk < 2; ++kk) {
            bf16x8 af[2], bfr[4];
#pragma unroll
            for (int mi = 0; mi < 2; ++mi)
                af[mi] = *reinterpret_cast<const bf16x8*>(&Al[(w * 32 + mi * 16 + l15) * 64 + kk * 32 + lg * 8]);
#pragma unroll
            for (int ni = 0; ni < 4; ++ni)
                bfr[ni] = *reinterpret_cast<const bf16x8*>(&Bl[(ni * 16 + l15) * 64 + kk * 32 + lg * 8]);
#pragma unroll
            for (int mi = 0; mi < 2; ++mi)
#pragma unroll
                for (int ni = 0; ni < 4; ++ni)
                    acc[mi][ni] = mfma16(af[mi], bfr[ni], acc[mi][ni]);
        }
        __syncthreads();
    }

#pragma unroll
    for (int mi = 0; mi < 2; ++mi)
#pragma unroll
        for (int r = 0; r < 4; ++r) {
            int m = mt * 128 + w * 32 + mi * 16 + lg * 4 + r;
#pragma unroll
            for (int ni = 0; ni < 4; ++ni) {
                int n = nt * 64 + ni * 16 + l15;
                outf[(size_t)m * 1024 + n] = acc[mi][ni][r];
            }
        }
}

// ---------------- causal flash attention ----------------------------------
// r4 skeleton (single-buffered K/V, 2 barriers/tile, reg prefetch,
// swapped-operand lane-local softmax) with 8-wave blocks: 512 thr =
// 8 waves x 16 q-rows (QBLK=128). 2 blocks/CU -> 16 waves/CU residency.
__global__ __launch_bounds__(512, 4) void flash_attn_kernel(
        const u16* __restrict__ Qh, const u16* __restrict__ Kh,
        const u16* __restrict__ Vt, u16* __restrict__ Ctx) {
    __shared__ u16 Ksh[64][72];
    __shared__ u16 Vsh[64][72];
    __shared__ u16 Psh[8][16][72];

    const int tid = threadIdx.x;
    const int l = tid & 63, w = tid >> 6;      // 8 waves
    const int l15 = l & 15, lg = l >> 4;

    const int bid = blockIdx.x;
    const int bh = bid & 31;                 // bh%8 pins to one XCD
    const int qt = 15 - (bid >> 5);          // big q-tiles dispatched first
    const int b = bh >> 4, h = bh & 15;
    const int qr0 = qt * 128 + w * 16;       // this wave's 16 q-rows

    // Q fragments (B-operand): lane holds Q[q=qr0+l15][32kk+8lg .. +7]
    const u16* qb = Qh + ((size_t)bh * Sc + qr0) * 64;
    bf16x8 aq[2];
#pragma unroll
    for (int kk = 0; kk < 2; ++kk)
        aq[kk] = *reinterpret_cast<const bf16x8*>(
            qb + (size_t)l15 * 64 + kk * 32 + lg * 8);

    // O^T accumulator: o[nd][r] = O[d=nd*16+4lg+r][q=l15]
    f32x4 o[4] = {};
    float m_run = -1e30f, l_run = 0.f;

    const u16* kb0 = Kh + (size_t)bh * Sc * 64;
    const u16* vb0 = Vt + (size_t)bh * 64 * Sc;
    const int nkt = 2 * qt + 2;              // block trip count
    const int kt_max_w = qr0 >> 6;           // this wave's last active tile

    uint4 rk, rv;
    auto load_kv = [&](int kt) {
        int r = tid >> 3, cc = (tid & 7) * 8;   // 512 thr cover 64x64 tile
        rk = *reinterpret_cast<const uint4*>(kb0 + ((size_t)kt * 64 + r) * 64 + cc);
        rv = *reinterpret_cast<const uint4*>(vb0 + (size_t)r * Sc + kt * 64 + cc);
    };
    auto store_kv = [&]() {
        int r = tid >> 3, cc = (tid & 7) * 8;
        *reinterpret_cast<uint4*>(&Ksh[r][cc]) = rk;
        *reinterpret_cast<uint4*>(&Vsh[r][cc]) = rv;
    };

    load_kv(0);
    for (int kt = 0; kt < nkt; ++kt) {
        store_kv();
        __syncthreads();
        if (kt + 1 < nkt) load_kv(kt + 1);   // prefetch overlaps compute

        if (kt <= kt_max_w) {
            // S^T = K Q^T: sc[nk][r] = S[q=l15][kpos=kt*64+16nk+4lg+r]
            f32x4 sc[4] = {};
#pragma unroll
            for (int kk = 0; kk < 2; ++kk) {
                bf16x8 kf[4];
#pragma unroll
                for (int nk = 0; nk < 4; ++nk)
                    kf[nk] = *reinterpret_cast<const bf16x8*>(&Ksh[nk * 16 + l15][kk * 32 + lg * 8]);
                __builtin_amdgcn_s_setprio(1);
#pragma unroll
                for (int nk = 0; nk < 4; ++nk)
                    sc[nk] = mfma16(kf[nk], aq[kk], sc[nk]);
                __builtin_amdgcn_s_setprio(0);
            }

            // causal mask only on this wave's diagonal tile
            if (kt == kt_max_w) {
                const int kb = kt * 64 + lg * 4;
                const int qg = qr0 + l15;
#pragma unroll
                for (int nk = 0; nk < 4; ++nk)
#pragma unroll
                    for (int r = 0; r < 4; ++r)
                        if (kb + nk * 16 + r > qg) sc[nk][r] = -1e30f;
            }

            // lane-local online softmax in exp2 domain (q = l15 lane-fixed)
            float pmax = -1e30f;
#pragma unroll
            for (int nk = 0; nk < 4; ++nk)
#pragma unroll
                for (int r = 0; r < 4; ++r) pmax = fmaxf(pmax, sc[nk][r]);
            pmax = fmaxf(pmax, __shfl_xor(pmax, 16));
            pmax = fmaxf(pmax, __shfl_xor(pmax, 32));
            if (pmax > m_run + 11.5f) {          // defer-max (~8 nats)
                float alpha = exp2f(m_run - pmax);
                l_run *= alpha;
#pragma unroll
                for (int nd = 0; nd < 4; ++nd)
#pragma unroll
                    for (int r = 0; r < 4; ++r) o[nd][r] *= alpha;
                m_run = pmax;
            }
            float ssum = 0.f;
#pragma unroll
            for (int nk = 0; nk < 4; ++nk)
#pragma unroll
                for (int r = 0; r < 4; ++r) {
                    float p = exp2f(sc[nk][r] - m_run);
                    sc[nk][r] = p;
                    ssum += p;
                }
            ssum += __shfl_xor(ssum, 16);
            ssum += __shfl_xor(ssum, 32);
            l_run += ssum;
            // pack P row (q=l15) -> Psh[w][q][kpos], 4x ds_write_b64
#pragma unroll
            for (int nk = 0; nk < 4; ++nk) {
                uint2 pk;
                pk.x = cvtpk_bf16(sc[nk][0], sc[nk][1]);
                pk.y = cvtpk_bf16(sc[nk][2], sc[nk][3]);
                *reinterpret_cast<uint2*>(&Psh[w][l15][nk * 16 + lg * 4]) = pk;
            }
            asm volatile("s_waitcnt lgkmcnt(0)" ::: "memory");
            __builtin_amdgcn_sched_barrier(0);

            // O^T += V^T P^T : mfma(V, P) -> D[d][q]
#pragma unroll
            for (int kk = 0; kk < 2; ++kk) {
                bf16x8 vf[4];
#pragma unroll
                for (int nd = 0; nd < 4; ++nd)
                    vf[nd] = *reinterpret_cast<const bf16x8*>(&Vsh[nd * 16 + l15][kk * 32 + lg * 8]);
                bf16x8 pa = *reinterpret_cast<const bf16x8*>(&Psh[w][l15][kk * 32 + lg * 8]);
                __builtin_amdgcn_s_setprio(1);
#pragma unroll
                for (int nd = 0; nd < 4; ++nd)
                    o[nd] = mfma16(vf[nd], pa, o[nd]);
                __builtin_amdgcn_s_setprio(0);
            }
        }
        __syncthreads();
    }

    // epilogue: normalize (per-lane q), write Ctx (B,S,D) bf16, 8B packed
    {
        float inv = 1.f / l_run;
        int srow = qr0 + l15;
        size_t base = ((size_t)b * Sc + srow) * Dc + h * 64;
#pragma unroll
        for (int nd = 0; nd < 4; ++nd) {
            uint2 pk;
            pk.x = cvtpk_bf16(o[nd][0] * inv, o[nd][1] * inv);
            pk.y = cvtpk_bf16(o[nd][2] * inv, o[nd][3] * inv);
            *reinterpret_cast<uint2*>(Ctx + base + nd * 16 + lg * 4) = pk;
        }
    }
}

// ---------------------------------------------------------------------------
extern "C" void kernel_launch(void* const* d_in, const int* in_sizes, int n_in,
                              void* d_out, int out_size, void* d_ws, size_t ws_size,
                              hipStream_t stream) {
    const float* q  = (const float*)d_in[0];
    const float* k  = (const float*)d_in[1];
    const float* v  = (const float*)d_in[2];
    const float* Wq = (const float*)d_in[4];
    const float* Wk = (const float*)d_in[5];
    const float* Wv = (const float*)d_in[6];
    const float* Wo = (const float*)d_in[7];

    u16* ws = (u16*)d_ws;
    u16* Xq  = ws;                       // 3 x 4M input bf16 (contiguous)
    u16* Wqb = ws + 3 * SEG4M;           // 4 x 1M weights bf16 (contiguous)
    u16* Wob = Wqb + 3 * SEG1M;
    u16* Qh  = ws + 4 * SEG4M;           // Q head-layout (exp2-scaled)
    u16* Kh  = Qh + SEG4M;               // K head-layout
    u16* Vtr = Kh + SEG4M;               // V TRANSPOSED (written by gemm_qkv)
    u16* Ctx = ws;                       // alias Xq (dead after gemm_qkv)

    // 1) all conversions, one launch
    cvt_all_kernel<<<8192, 256, 0, stream>>>(q, k, v, Wq, Wk, Wv, Wo, ws);

    // 2) fused QKV projection (Q scaled 0.125*log2e; V written pre-transposed)
    gemm_qkv_kernel<<<768, 256, 0, stream>>>(Xq, Wqb, Qh);

    // 3) causal flash attention (8-wave blocks, single-buffered K/V)
    flash_attn_kernel<<<512, 512, 0, stream>>>(Qh, Kh, Vtr, Ctx);

    // 4) output projection -> fp32
    gemm_out_kernel<<<512, 256, 0, stream>>>(Ctx, Wob, (float*)d_out);
}

// Round 7
// 123.830 us; speedup vs baseline: 1.2737x; 1.0009x over previous
//
#include <hip/hip_runtime.h>
#include <hip/hip_bf16.h>
#include <stdint.h>

#define DEV_INLINE __device__ __forceinline__

typedef unsigned short u16;
typedef __attribute__((ext_vector_type(8))) __bf16 bf16x8;
typedef __attribute__((ext_vector_type(4))) float f32x4;
typedef __attribute__((ext_vector_type(16))) float f32x16;

constexpr int Bc = 2, Sc = 2048, Dc = 1024, Hc = 16, HDc = 64;
constexpr int Kdim = 1024;
constexpr size_t SEG4M = 4194304;   // 4M elems
constexpr size_t SEG1M = 1048576;   // 1M elems

DEV_INLINE u16 f32_to_bf16(float f) {
    unsigned int u = __builtin_bit_cast(unsigned int, f);
    unsigned int r = (u + 0x7fffu + ((u >> 16) & 1u)) >> 16;
    return (u16)r;
}

// v_cvt_pk_bf16_f32: low16 = bf16(lo), high16 = bf16(hi)
DEV_INLINE uint32_t cvtpk_bf16(float lo, float hi) {
    uint32_t r;
    asm("v_cvt_pk_bf16_f32 %0, %1, %2" : "=v"(r) : "v"(lo), "v"(hi));
    return r;
}

DEV_INLINE f32x4 mfma16(bf16x8 a, bf16x8 b, f32x4 c) {
    return __builtin_amdgcn_mfma_f32_16x16x32_bf16(a, b, c, 0, 0, 0);
}
DEV_INLINE f32x16 mfma32(bf16x8 a, bf16x8 b, f32x16 c) {
    return __builtin_amdgcn_mfma_f32_32x32x16_bf16(a, b, c, 0, 0, 0);
}

// async global->LDS, 16B per lane; lds dest must be wave-uniform base.
DEV_INLINE void gload_lds16(const u16* g, u16* lds) {
    __builtin_amdgcn_global_load_lds(
        (const __attribute__((address_space(1))) void*)g,
        (__attribute__((address_space(3))) void*)lds,
        16, 0, 0);
}

// ---------------- fp32 -> bf16, all 7 tensors in one launch ----------------
__global__ __launch_bounds__(256) void cvt_all_kernel(
        const float* __restrict__ q, const float* __restrict__ k,
        const float* __restrict__ v, const float* __restrict__ wq,
        const float* __restrict__ wk, const float* __restrict__ wv,
        const float* __restrict__ wo, u16* __restrict__ dst) {
    int b = blockIdx.x;
    const float* src; size_t doff; int lb;
    if (b < 2048)      { src = q;  lb = b;        doff = 0; }
    else if (b < 4096) { src = k;  lb = b - 2048; doff = SEG4M; }
    else if (b < 6144) { src = v;  lb = b - 4096; doff = 2 * SEG4M; }
    else if (b < 6656) { src = wq; lb = b - 6144; doff = 3 * SEG4M; }
    else if (b < 7168) { src = wk; lb = b - 6656; doff = 3 * SEG4M + SEG1M; }
    else if (b < 7680) { src = wv; lb = b - 7168; doff = 3 * SEG4M + 2 * SEG1M; }
    else               { src = wo; lb = b - 7680; doff = 3 * SEG4M + 3 * SEG1M; }
    size_t i = ((size_t)lb * 256 + threadIdx.x) * 8;
    float4 a = *reinterpret_cast<const float4*>(src + i);
    float4 c = *reinterpret_cast<const float4*>(src + i + 4);
    union { u16 u[8]; uint4 v4; } o;
    o.u[0] = f32_to_bf16(a.x); o.u[1] = f32_to_bf16(a.y);
    o.u[2] = f32_to_bf16(a.z); o.u[3] = f32_to_bf16(a.w);
    o.u[4] = f32_to_bf16(c.x); o.u[5] = f32_to_bf16(c.y);
    o.u[6] = f32_to_bf16(c.z); o.u[7] = f32_to_bf16(c.w);
    *reinterpret_cast<uint4*>(dst + doff + i) = o.v4;
}

// ---------------- fused QKV projection: 128x128 tiles, global_load_lds -----
// seg 0 -> Qh head-layout (scaled 1/8 * log2(e) for exp2-domain softmax);
// seg 1 -> Kh head-layout; seg 2 -> Vt TRANSPOSED (BH,64,S).
__global__ __launch_bounds__(256, 3) void gemm_qkv_kernel(
        const u16* __restrict__ Xb, const u16* __restrict__ Wb,
        u16* __restrict__ Ob) {
    __shared__ u16 Al[128 * 64];
    __shared__ u16 Bl[128 * 64];
    const int tid = threadIdx.x;
    const int l = tid & 63, w = tid >> 6;
    const int wm = w >> 1, wn = w & 1;
    const int l15 = l & 15, lg = l >> 4;
    const int lr = l >> 3, lc = (l & 7) * 8;

    int bid = blockIdx.x;                       // 768 blocks
    int wid = (bid & 7) * 96 + (bid >> 3);      // XCD-contiguous
    int mt = wid / 24, nt = wid % 24;
    int seg = nt >> 3, ntl = nt & 7;

    const u16* A = Xb + (size_t)seg * SEG4M + (size_t)mt * 128 * Kdim;
    const u16* W = Wb + (size_t)seg * SEG1M + (size_t)ntl * 128 * Kdim;

    f32x4 acc[4][4] = {};

    for (int kt = 0; kt < 16; ++kt) {
        const int kb = kt * 64;
#pragma unroll
        for (int i = 0; i < 4; ++i) {
            int j = w * 4 + i;
            gload_lds16(A + (size_t)(j * 8 + lr) * Kdim + kb + lc, &Al[j * 512]);
            gload_lds16(W + (size_t)(j * 8 + lr) * Kdim + kb + lc, &Bl[j * 512]);
        }
        asm volatile("s_waitcnt vmcnt(0)" ::: "memory");
        __syncthreads();
#pragma unroll
        for (int kk = 0; kk < 2; ++kk) {
            bf16x8 af[4], bfr[4];
#pragma unroll
            for (int mi = 0; mi < 4; ++mi)
                af[mi] = *reinterpret_cast<const bf16x8*>(&Al[(wm * 64 + mi * 16 + l15) * 64 + kk * 32 + lg * 8]);
#pragma unroll
            for (int ni = 0; ni < 4; ++ni)
                bfr[ni] = *reinterpret_cast<const bf16x8*>(&Bl[(wn * 64 + ni * 16 + l15) * 64 + kk * 32 + lg * 8]);
#pragma unroll
            for (int mi = 0; mi < 4; ++mi)
#pragma unroll
                for (int ni = 0; ni < 4; ++ni)
                    acc[mi][ni] = mfma16(af[mi], bfr[ni], acc[mi][ni]);
        }
        __syncthreads();
    }

    const int row0 = mt * 128 + wm * 64;
    const int col0 = ntl * 128 + wn * 64;

    if (seg == 2) {
        // V: write transposed Vt[(bh*64+d)*Sc + s], 4 s-consecutive packed
        u16* outT = Ob + 2 * SEG4M;
#pragma unroll
        for (int mi = 0; mi < 4; ++mi) {
            int m0 = row0 + mi * 16 + lg * 4;    // s base (4 consecutive)
            int b = m0 >> 11, s0 = m0 & 2047;
#pragma unroll
            for (int ni = 0; ni < 4; ++ni) {
                int n = col0 + ni * 16 + l15;
                int h = n >> 6, d = n & 63;
                int bh = b * Hc + h;
                uint2 pk;
                pk.x = ((uint32_t)f32_to_bf16(acc[mi][ni][1]) << 16) | f32_to_bf16(acc[mi][ni][0]);
                pk.y = ((uint32_t)f32_to_bf16(acc[mi][ni][3]) << 16) | f32_to_bf16(acc[mi][ni][2]);
                *reinterpret_cast<uint2*>(outT + ((size_t)bh * 64 + d) * Sc + s0) = pk;
            }
        }
    } else {
        // Q scaled into exp2 domain: 1/sqrt(64) * log2(e)
        const float scale = (seg == 0) ? 0.18033688f : 1.0f;
        u16* out = Ob + (size_t)seg * SEG4M;
#pragma unroll
        for (int mi = 0; mi < 4; ++mi)
#pragma unroll
            for (int r = 0; r < 4; ++r) {
                int m = row0 + mi * 16 + lg * 4 + r;
                int b = m >> 11, s = m & 2047;
#pragma unroll
                for (int ni = 0; ni < 4; ++ni) {
                    int n = col0 + ni * 16 + l15;
                    int h = n >> 6, d = n & 63;
                    out[(((size_t)b * Hc + h) * Sc + s) * HDc + d] =
                        f32_to_bf16(acc[mi][ni][r] * scale);
                }
            }
    }
}

// ---------------- output projection: 128x64 tiles -> fp32 ------------------
__global__ __launch_bounds__(256, 3) void gemm_out_kernel(
        const u16* __restrict__ A0, const u16* __restrict__ W0,
        float* __restrict__ outf) {
    __shared__ u16 Al[128 * 64];
    __shared__ u16 Bl[64 * 64];
    const int tid = threadIdx.x;
    const int l = tid & 63, w = tid >> 6;
    const int l15 = l & 15, lg = l >> 4;
    const int lr = l >> 3, lc = (l & 7) * 8;

    int bid = blockIdx.x;                      // 512 blocks
    int wid = (bid & 7) * 64 + (bid >> 3);
    int mt = wid >> 4, nt = wid & 15;

    const u16* A = A0 + (size_t)mt * 128 * Kdim;
    const u16* W = W0 + (size_t)nt * 64 * Kdim;

    f32x4 acc[2][4] = {};

    for (int kt = 0; kt < 16; ++kt) {
        const int kb = kt * 64;
#pragma unroll
        for (int i = 0; i < 4; ++i) {
            int j = w * 4 + i;
            gload_lds16(A + (size_t)(j * 8 + lr) * Kdim + kb + lc, &Al[j * 512]);
        }
#pragma unroll
        for (int i = 0; i < 2; ++i) {
            int j = w * 2 + i;
            gload_lds16(W + (size_t)(j * 8 + lr) * Kdim + kb + lc, &Bl[j * 512]);
        }
        asm volatile("s_waitcnt vmcnt(0)" ::: "memory");
        __syncthreads();
#pragma unroll
        for (int kk = 0; kk < 2; ++kk) {
            bf16x8 af[2], bfr[4];
#pragma unroll
            for (int mi = 0; mi < 2; ++mi)
                af[mi] = *reinterpret_cast<const bf16x8*>(&Al[(w * 32 + mi * 16 + l15) * 64 + kk * 32 + lg * 8]);
#pragma unroll
            for (int ni = 0; ni < 4; ++ni)
                bfr[ni] = *reinterpret_cast<const bf16x8*>(&Bl[(ni * 16 + l15) * 64 + kk * 32 + lg * 8]);
#pragma unroll
            for (int mi = 0; mi < 2; ++mi)
#pragma unroll
                for (int ni = 0; ni < 4; ++ni)
                    acc[mi][ni] = mfma16(af[mi], bfr[ni], acc[mi][ni]);
        }
        __syncthreads();
    }

#pragma unroll
    for (int mi = 0; mi < 2; ++mi)
#pragma unroll
        for (int r = 0; r < 4; ++r) {
            int m = mt * 128 + w * 32 + mi * 16 + lg * 4 + r;
#pragma unroll
            for (int ni = 0; ni < 4; ++ni) {
                int n = nt * 64 + ni * 16 + l15;
                outf[(size_t)m * 1024 + n] = acc[mi][ni][r];
            }
        }
}

// ---------------- causal flash attention: 32x32 MFMA, in-register P --------
// Qh,Kh: (BH,S,64) bf16 (Q pre-scaled by 0.125*log2e); Vt: (BH,64,S) bf16.
// Grid 512 = 16 qt x 32 bh; block = 4 waves x 32 q-rows (QBLK=128), KVBLK=64.
// S^T = mfma32(K,Q): lane owns one q-col, 32 of 64 kpos (partner lane l^32
// owns the rest). Softmax: 31 fmax + 1 shfl. P re-fragmented IN REGISTER
// (cvt_pk + shfl_xor(32) + cndmask) -> no P LDS roundtrip, no lgkmcnt stall.
// PV = mfma32(V^T, P) -> O^T accumulator.
__global__ __launch_bounds__(256, 2) void flash_attn_kernel(
        const u16* __restrict__ Qh, const u16* __restrict__ Kh,
        const u16* __restrict__ Vt, u16* __restrict__ Ctx) {
    __shared__ u16 Ksh[64][72];
    __shared__ u16 Vsh[64][72];

    const int tid = threadIdx.x;
    const int l = tid & 63, w = tid >> 6;     // 4 waves
    const int l31 = l & 31;
    const int h = l >> 5;                     // wave half

    const int bid = blockIdx.x;
    const int bh = bid & 31;                  // bh%8 pins to one XCD
    const int qt = 15 - (bid >> 5);           // big q-tiles dispatched first
    const int b = bh >> 4, hh = bh & 15;
    const int qr0 = qt * 128 + w * 32;        // this wave's 32 q-rows
    const int q = qr0 + l31;                  // this lane's q row

    // Q fragments (B-operand of mfma32): aq[s][j] = Q[q][d=16s+8h+j]
    const u16* qb = Qh + ((size_t)bh * Sc + q) * 64;
    bf16x8 aq[4];
#pragma unroll
    for (int s = 0; s < 4; ++s)
        aq[s] = *reinterpret_cast<const bf16x8*>(qb + s * 16 + h * 8);

    // O^T accumulator: o[nd][r] = O[d = 32nd + (r&3)+8(r>>2)+4h][q]
    f32x16 o[2] = {};
    float m_run = -1e30f, l_run = 0.f;

    const u16* kb0 = Kh + (size_t)bh * Sc * 64;
    const u16* vb0 = Vt + (size_t)bh * 64 * Sc;
    const int nkt = 2 * qt + 2;               // block trip count
    const int kt_max_w = qr0 >> 6;            // this wave's last active tile

    uint4 rk, rv;
    auto load_kv = [&](int kt) {
        int r = tid >> 3, cc = (tid & 7) * 8;     // 256 thr x 2 shots = 64x64
        rk = *reinterpret_cast<const uint4*>(kb0 + ((size_t)kt * 64 + r) * 64 + cc);
        rv = *reinterpret_cast<const uint4*>(vb0 + (size_t)r * Sc + kt * 64 + cc);
    };
    uint4 rk2, rv2;
    auto load_kv2 = [&](int kt) {
        int r = 32 + (tid >> 3), cc = (tid & 7) * 8;
        rk2 = *reinterpret_cast<const uint4*>(kb0 + ((size_t)kt * 64 + r) * 64 + cc);
        rv2 = *reinterpret_cast<const uint4*>(vb0 + (size_t)r * Sc + kt * 64 + cc);
    };
    auto store_kv = [&]() {
        int r = tid >> 3, cc = (tid & 7) * 8;
        *reinterpret_cast<uint4*>(&Ksh[r][cc]) = rk;
        *reinterpret_cast<uint4*>(&Vsh[r][cc]) = rv;
        *reinterpret_cast<uint4*>(&Ksh[32 + r][cc]) = rk2;
        *reinterpret_cast<uint4*>(&Vsh[32 + r][cc]) = rv2;
    };

    load_kv(0); load_kv2(0);
    for (int kt = 0; kt < nkt; ++kt) {
        store_kv();
        __syncthreads();
        if (kt + 1 < nkt) { load_kv(kt + 1); load_kv2(kt + 1); }

        if (kt <= kt_max_w) {
            // S^T = K Q^T: sc[nk] covers kpos block nk*32 (rows), col = q
            f32x16 sc[2] = {};
#pragma unroll
            for (int s = 0; s < 4; ++s) {
                bf16x8 kf0 = *reinterpret_cast<const bf16x8*>(&Ksh[l31][s * 16 + h * 8]);
                bf16x8 kf1 = *reinterpret_cast<const bf16x8*>(&Ksh[32 + l31][s * 16 + h * 8]);
                __builtin_amdgcn_s_setprio(1);
                sc[0] = mfma32(kf0, aq[s], sc[0]);
                sc[1] = mfma32(kf1, aq[s], sc[1]);
                __builtin_amdgcn_s_setprio(0);
            }

            // causal mask only on this wave's diagonal tile
            if (kt == kt_max_w) {
#pragma unroll
                for (int nk = 0; nk < 2; ++nk)
#pragma unroll
                    for (int r = 0; r < 16; ++r) {
                        int kpos = kt * 64 + nk * 32 + (r & 3) + 8 * (r >> 2) + 4 * h;
                        if (kpos > q) sc[nk][r] = -1e30f;
                    }
            }

            // lane-local online softmax in exp2 domain; lane^32 holds the
            // complementary 32 kpos of the same q row -> one shfl combines.
            float pmax = -1e30f;
#pragma unroll
            for (int nk = 0; nk < 2; ++nk)
#pragma unroll
                for (int r = 0; r < 16; ++r) pmax = fmaxf(pmax, sc[nk][r]);
            pmax = fmaxf(pmax, __shfl_xor(pmax, 32));
            if (pmax > m_run + 11.5f) {           // defer-max (~8 nats)
                float alpha = exp2f(m_run - pmax);
                l_run *= alpha;
#pragma unroll
                for (int nd = 0; nd < 2; ++nd)
#pragma unroll
                    for (int r = 0; r < 16; ++r) o[nd][r] *= alpha;
                m_run = pmax;
            }
            float ssum = 0.f;
#pragma unroll
            for (int nk = 0; nk < 2; ++nk)
#pragma unroll
                for (int r = 0; r < 16; ++r) {
                    float p = exp2f(sc[nk][r] - m_run);
                    sc[nk][r] = p;
                    ssum += p;
                }
            ssum += __shfl_xor(ssum, 32);
            l_run += ssum;

            // ---- in-register P -> PV B-fragments ----
            // pack pairs: pk[nk][t] = bf16x2 of kpos32 {base, base+1}
            uint32_t pk0[8], pk1[8];
#pragma unroll
            for (int t = 0; t < 8; ++t) {
                pk0[t] = cvtpk_bf16(sc[0][2 * t], sc[0][2 * t + 1]);
                pk1[t] = cvtpk_bf16(sc[1][2 * t], sc[1][2 * t + 1]);
            }
            // exchange with partner half (l^32)
            uint32_t px0[8], px1[8];
#pragma unroll
            for (int t = 0; t < 8; ++t) {
                px0[t] = __shfl_xor(pk0[t], 32);
                px1[t] = __shfl_xor(pk1[t], 32);
            }
            // build frag[s]: P[kpos=16s+8h+j][q], j=0..7 (4 dwords each)
            union fragu { uint32_t d[4]; bf16x8 v; };
            fragu fr[4];
            // s=0: kpos 0-15 (nk=0): h0 {own 0-3, part 4-7}; h1 {part 8-11, own 12-15}
            fr[0].d[0] = h ? px0[2] : pk0[0];
            fr[0].d[1] = h ? px0[3] : pk0[1];
            fr[0].d[2] = h ? pk0[2] : px0[0];
            fr[0].d[3] = h ? pk0[3] : px0[1];
            // s=1: kpos 16-31 (nk=0 regs 8-15)
            fr[1].d[0] = h ? px0[6] : pk0[4];
            fr[1].d[1] = h ? px0[7] : pk0[5];
            fr[1].d[2] = h ? pk0[6] : px0[4];
            fr[1].d[3] = h ? pk0[7] : px0[5];
            // s=2: kpos 32-47 (nk=1)
            fr[2].d[0] = h ? px1[2] : pk1[0];
            fr[2].d[1] = h ? px1[3] : pk1[1];
            fr[2].d[2] = h ? pk1[2] : px1[0];
            fr[2].d[3] = h ? pk1[3] : px1[1];
            // s=3: kpos 48-63 (nk=1 regs 8-15)
            fr[3].d[0] = h ? px1[6] : pk1[4];
            fr[3].d[1] = h ? px1[7] : pk1[5];
            fr[3].d[2] = h ? pk1[6] : px1[4];
            fr[3].d[3] = h ? pk1[7] : px1[5];

            // O^T += V^T P : A = V^T[d][kpos], B = P[kpos][q]
#pragma unroll
            for (int s = 0; s < 4; ++s) {
                bf16x8 vf0 = *reinterpret_cast<const bf16x8*>(&Vsh[l31][s * 16 + h * 8]);
                bf16x8 vf1 = *reinterpret_cast<const bf16x8*>(&Vsh[32 + l31][s * 16 + h * 8]);
                __builtin_amdgcn_s_setprio(1);
                o[0] = mfma32(vf0, fr[s].v, o[0]);
                o[1] = mfma32(vf1, fr[s].v, o[1]);
                __builtin_amdgcn_s_setprio(0);
            }
        }
        __syncthreads();
    }

    // epilogue: normalize (per-lane q), write Ctx (B,S,D) bf16, 8B packed
    {
        float inv = 1.f / l_run;
        size_t base = ((size_t)b * Sc + q) * Dc + hh * 64;
#pragma unroll
        for (int nd = 0; nd < 2; ++nd)
#pragma unroll
            for (int g = 0; g < 4; ++g) {
                int d0 = nd * 32 + g * 8 + h * 4;
                uint2 pkt;
                pkt.x = cvtpk_bf16(o[nd][4 * g] * inv, o[nd][4 * g + 1] * inv);
                pkt.y = cvtpk_bf16(o[nd][4 * g + 2] * inv, o[nd][4 * g + 3] * inv);
                *reinterpret_cast<uint2*>(Ctx + base + d0) = pkt;
            }
    }
}

// ---------------------------------------------------------------------------
extern "C" void kernel_launch(void* const* d_in, const int* in_sizes, int n_in,
                              void* d_out, int out_size, void* d_ws, size_t ws_size,
                              hipStream_t stream) {
    const float* q  = (const float*)d_in[0];
    const float* k  = (const float*)d_in[1];
    const float* v  = (const float*)d_in[2];
    const float* Wq = (const float*)d_in[4];
    const float* Wk = (const float*)d_in[5];
    const float* Wv = (const float*)d_in[6];
    const float* Wo = (const float*)d_in[7];

    u16* ws = (u16*)d_ws;
    u16* Xq  = ws;                       // 3 x 4M input bf16 (contiguous)
    u16* Wqb = ws + 3 * SEG4M;           // 4 x 1M weights bf16 (contiguous)
    u16* Wob = Wqb + 3 * SEG1M;
    u16* Qh  = ws + 4 * SEG4M;           // Q head-layout (exp2-scaled)
    u16* Kh  = Qh + SEG4M;               // K head-layout
    u16* Vtr = Kh + SEG4M;               // V TRANSPOSED (written by gemm_qkv)
    u16* Ctx = ws;                       // alias Xq (dead after gemm_qkv)

    // 1) all conversions, one launch
    cvt_all_kernel<<<8192, 256, 0, stream>>>(q, k, v, Wq, Wk, Wv, Wo, ws);

    // 2) fused QKV projection (Q scaled 0.125*log2e; V written pre-transposed)
    gemm_qkv_kernel<<<768, 256, 0, stream>>>(Xq, Wqb, Qh);

    // 3) causal flash attention (32x32 MFMA, in-register P)
    flash_attn_kernel<<<512, 256, 0, stream>>>(Qh, Kh, Vtr, Ctx);

    // 4) output projection -> fp32
    gemm_out_kernel<<<512, 256, 0, stream>>>(Ctx, Wob, (float*)d_out);
}